// Round 1
// baseline (79.402 us; speedup 1.0000x reference)
//
#include <hip/hip_runtime.h>
#include <hip/hip_bf16.h>

// Resonance synth:
//   out(b,e,n) = sum_f env_f(n) * sin(2*pi*freq_f*(n+1))
//   freq_f = (MIN + SCALE*f0_be) * (f+1), zeroed if >= 1.0
//   env_f(n) = linear frame->sample interp of res_bef^(t+1), t=0..127
// B*E = 64 pairs, F = 32 harmonics, N = 32768 samples.

#define NSAMP 32768
#define NFRM  128
#define NF    32
#define NPAIR 64
#define CHUNKS 16
#define CHUNK_SAMP (NSAMP / CHUNKS)   // 2048
#define ITERS (CHUNK_SAMP / 256)      // 8

// Runtime-dtype input load: bf16 or f32, selected by wave-uniform flag.
__device__ __forceinline__ float ldin(const void* p, int i, bool isbf) {
    if (isbf) {
        unsigned int w = ((unsigned int)((const unsigned short*)p)[i]) << 16;
        float f;
        __builtin_memcpy(&f, &w, 4);
        return f;
    }
    return ((const float*)p)[i];
}

extern "C" __global__ __launch_bounds__(256)
void reson_kernel(const void* __restrict__ f0p,
                  const void* __restrict__ resp,
                  const void* __restrict__ facp,
                  void* __restrict__ outp)
{
    // dtype sniff: factors[0] == 1.0f. As f32 the first word is 0x3F800000;
    // as bf16 the first word packs (1.0bf16, 2.0bf16) = 0x40003F80.
    const bool isbf = (((const unsigned int*)facp)[0] != 0x3F800000u);

    const int pair = blockIdx.x;       // 0..63  (b*16 + e)
    const int tid  = threadIdx.x;      // 0..255

    __shared__ float P[NFRM * NF];     // P[t*32 + f] = res_f^(t+1), 16 KB
    __shared__ float FQ[NF];           // per-harmonic normalized frequency

    const float MINF = (float)(40.0 / 11025.0);
    const float FSC  = (float)(3960.0 / 11025.0);

    if (tid < NF) {
        float f0v = ldin(f0p, pair, isbf);           // f0 shape (4,16,1)
        float sf0 = MINF + FSC * f0v;
        float fac = ldin(facp, tid, isbf);           // factors 1..32
        float fr  = sf0 * fac;
        if (fr >= 1.0f) fr = 0.0f;                   // alias-zeroing
        FQ[tid] = fr;
    }
    // Envelope power table: P[t][f] = res^(t+1)
    for (int idx = tid; idx < NFRM * NF; idx += 256) {
        int t = idx >> 5;
        int f = idx & 31;
        float r = ldin(resp, pair * NF + f, isbf);   // res shape (4,16,32)
        P[idx] = exp2f(log2f(r) * (float)(t + 1));
    }
    __syncthreads();

    const int base = blockIdx.y * CHUNK_SAMP;

    for (int k = 0; k < ITERS; ++k) {
        const int n = base + k * 256 + tid;
        // frame-interp coords (align_corners=False): (n+0.5)/256 - 0.5, clip
        float c = (n + 0.5f) * (1.0f / 256.0f) - 0.5f;
        c = fminf(fmaxf(c, 0.0f), (float)(NFRM - 1));
        const int   i0 = (int)c;                     // floor, c >= 0
        const int   i1 = min(i0 + 1, NFRM - 1);
        const float w  = c - (float)i0;
        const float* __restrict__ P0 = &P[i0 * NF];
        const float* __restrict__ P1 = &P[i1 * NF];

        const double np1 = (double)(n + 1);
        float acc = 0.0f;
        #pragma unroll
        for (int f = 0; f < NF; ++f) {
            float env = P0[f] * (1.0f - w) + P1[f] * w;
            // closed-form phase in turns, f64 for drift-free accuracy
            double t = (double)FQ[f] * np1;
            t -= floor(t);
            // v_sin_f32 takes input in REVOLUTIONS: sin(2*pi*x)
            float s = __builtin_amdgcn_sinf((float)t);
            acc = fmaf(env, s, acc);
        }

        const int o = pair * NSAMP + n;
        if (isbf) ((__hip_bfloat16*)outp)[o] = __float2bfloat16(acc);
        else      ((float*)outp)[o] = acc;
    }
}

extern "C" void kernel_launch(void* const* d_in, const int* in_sizes, int n_in,
                              void* d_out, int out_size, void* d_ws, size_t ws_size,
                              hipStream_t stream) {
    (void)in_sizes; (void)n_in; (void)out_size; (void)d_ws; (void)ws_size;
    dim3 grid(NPAIR, CHUNKS);   // 64 x 16 = 1024 blocks, 4096 waves
    dim3 block(256);
    reson_kernel<<<grid, block, 0, stream>>>(d_in[0], d_in[1], d_in[2], d_out);
}